// Round 1
// baseline (323.885 us; speedup 1.0000x reference)
//
#include <hip/hip_runtime.h>

// Problem constants
#define N_SAMP 1024
#define XC_DIM 512
#define YC_DIM 256
#define HID_DIM 512
// spatial = 8*8 = 64 floats per (sample, channel), contiguous in memory

// ---------------------------------------------------------------------------
// K1: fused spatial pooling for x and y.
// Each wave handles 64 consecutive outputs = 64*64 floats = 16 KB contiguous.
// Loads are perfectly coalesced float4 (1024 B per wave instruction); groups
// of 16 lanes shuffle-reduce to one output each per j-iteration.
// ---------------------------------------------------------------------------
__global__ __launch_bounds__(256) void pool_kernel(
    const float* __restrict__ x, const float* __restrict__ y,
    float* __restrict__ x_vec, float* __restrict__ y_vec) {
  const int tid  = blockIdx.x * blockDim.x + threadIdx.x;
  const int wave = tid >> 6;
  const int lane = threadIdx.x & 63;
  const int XWAVES = (N_SAMP * XC_DIM) / 64;  // 8192

  const float4* src;
  float* dst;
  long base;
  if (wave < XWAVES) {
    base = (long)wave * 64;
    src = (const float4*)x;
    dst = x_vec;
  } else {
    base = (long)(wave - XWAVES) * 64;
    src = (const float4*)y;
    dst = y_vec;
  }
  const float4* p = src + base * 16;  // 16 float4 per output element

#pragma unroll
  for (int j = 0; j < 16; ++j) {
    float4 v = p[j * 64 + lane];
    float s = (v.x + v.y) + (v.z + v.w);
    s += __shfl_xor(s, 1);
    s += __shfl_xor(s, 2);
    s += __shfl_xor(s, 4);
    s += __shfl_xor(s, 8);
    if ((lane & 15) == 0) dst[base + j * 4 + (lane >> 4)] = s * (1.0f / 64.0f);
  }
}

// ---------------------------------------------------------------------------
// K2: h = relu(x_vec @ W1 + b1).  M=1024, K=512, N=512, fp32 vector ALU.
// BM=64, BN=32, BK=16, 256 threads, per-thread 4x2. Grid 16x16 = 256 blocks.
// ---------------------------------------------------------------------------
#define G1_BM 64
#define G1_BN 32
#define G1_BK 16

__global__ __launch_bounds__(256) void gemm1_kernel(
    const float* __restrict__ A, const float* __restrict__ B,
    const float* __restrict__ bias, float* __restrict__ C) {
  const int K = 512, Nn = 512;
  __shared__ float As[G1_BK][G1_BM];  // transposed A tile
  __shared__ float Bs[G1_BK][G1_BN];
  const int t = threadIdx.x;
  const int bm = blockIdx.y * G1_BM;
  const int bn = blockIdx.x * G1_BN;

  const int ar = t >> 2;        // 0..63 : A tile row
  const int ac = (t & 3) * 4;   // 0,4,8,12 : A tile col (float4)
  const int br = t >> 4;        // 0..15 : B tile row
  const int bc = (t & 15) * 2;  // 0..30 : B tile col (float2)

  const int row0 = (t >> 4) * 4;  // 0..60
  const int col0 = (t & 15) * 2;  // 0..30

  float acc[4][2] = {};

  for (int k0 = 0; k0 < K; k0 += G1_BK) {
    float4 av = *(const float4*)&A[(bm + ar) * K + k0 + ac];
    float2 bv = *(const float2*)&B[(k0 + br) * Nn + bn + bc];
    __syncthreads();
    As[ac + 0][ar] = av.x;
    As[ac + 1][ar] = av.y;
    As[ac + 2][ar] = av.z;
    As[ac + 3][ar] = av.w;
    *(float2*)&Bs[br][bc] = bv;
    __syncthreads();
#pragma unroll
    for (int kk = 0; kk < G1_BK; ++kk) {
      float4 a = *(const float4*)&As[kk][row0];
      float2 b = *(const float2*)&Bs[kk][col0];
      acc[0][0] += a.x * b.x; acc[0][1] += a.x * b.y;
      acc[1][0] += a.y * b.x; acc[1][1] += a.y * b.y;
      acc[2][0] += a.z * b.x; acc[2][1] += a.z * b.y;
      acc[3][0] += a.w * b.x; acc[3][1] += a.w * b.y;
    }
  }

  const float bb0 = bias[bn + col0];
  const float bb1 = bias[bn + col0 + 1];
#pragma unroll
  for (int i = 0; i < 4; ++i) {
    float2 o;
    o.x = fmaxf(acc[i][0] + bb0, 0.0f);
    o.y = fmaxf(acc[i][1] + bb1, 0.0f);
    *(float2*)&C[(bm + row0 + i) * Nn + bn + col0] = o;
  }
}

// ---------------------------------------------------------------------------
// K3: mu = h @ W2 + b2 (never materialized).  M=1024, K=512, N=256.
// Fused epilogue: dot += mu.*y_vec ; colsum_mu[d] += mu ; colsum_y[d] += y.
// BM=32, BN=32, BK=16, 256 threads, per-thread 2x2. Grid 8x32 = 256 blocks.
// ---------------------------------------------------------------------------
#define G2_BM 32
#define G2_BN 32
#define G2_BK 16

__global__ __launch_bounds__(256) void gemm2_kernel(
    const float* __restrict__ A, const float* __restrict__ B,
    const float* __restrict__ bias, const float* __restrict__ yvec,
    float* __restrict__ colsum_mu, float* __restrict__ colsum_y,
    float* __restrict__ dot_out) {
  const int K = 512, Nn = 256;
  __shared__ float As[G2_BK][G2_BM];
  __shared__ float Bs[G2_BK][G2_BN];
  __shared__ float s_mu[G2_BN];
  __shared__ float s_y[G2_BN];
  const int t = threadIdx.x;
  const int bm = blockIdx.y * G2_BM;
  const int bn = blockIdx.x * G2_BN;
  if (t < G2_BN) { s_mu[t] = 0.0f; s_y[t] = 0.0f; }

  const int ar = t >> 3;        // 0..31
  const int ac = (t & 7) * 2;   // 0..14 (float2 along K)
  const int br = t >> 4;        // 0..15
  const int bc = (t & 15) * 2;  // 0..30

  const int row0 = (t >> 4) * 2;  // 0..30
  const int col0 = (t & 15) * 2;  // 0..30

  float acc[2][2] = {};

  for (int k0 = 0; k0 < K; k0 += G2_BK) {
    float2 av = *(const float2*)&A[(bm + ar) * K + k0 + ac];
    float2 bv = *(const float2*)&B[(k0 + br) * Nn + bn + bc];
    __syncthreads();
    As[ac + 0][ar] = av.x;
    As[ac + 1][ar] = av.y;
    *(float2*)&Bs[br][bc] = bv;
    __syncthreads();
#pragma unroll
    for (int kk = 0; kk < G2_BK; ++kk) {
      float2 a = *(const float2*)&As[kk][row0];
      float2 b = *(const float2*)&Bs[kk][col0];
      acc[0][0] += a.x * b.x; acc[0][1] += a.x * b.y;
      acc[1][0] += a.y * b.x; acc[1][1] += a.y * b.y;
    }
  }

  // Epilogue: mu = acc + b2; accumulate dot, colsums. mu is never stored.
  const float b2a = bias[bn + col0];
  const float b2b = bias[bn + col0 + 1];
  float dotp = 0.0f, cm0 = 0.0f, cm1 = 0.0f, cy0 = 0.0f, cy1 = 0.0f;
#pragma unroll
  for (int i = 0; i < 2; ++i) {
    const int gi = bm + row0 + i;
    float2 yv2 = *(const float2*)&yvec[gi * Nn + bn + col0];
    float mu0 = acc[i][0] + b2a;
    float mu1 = acc[i][1] + b2b;
    dotp += mu0 * yv2.x + mu1 * yv2.y;
    cm0 += mu0; cm1 += mu1;
    cy0 += yv2.x; cy1 += yv2.y;
  }
  atomicAdd(&s_mu[col0], cm0);
  atomicAdd(&s_mu[col0 + 1], cm1);
  atomicAdd(&s_y[col0], cy0);
  atomicAdd(&s_y[col0 + 1], cy1);
#pragma unroll
  for (int off = 1; off < 64; off <<= 1) dotp += __shfl_xor(dotp, off);
  if ((t & 63) == 0) atomicAdd(dot_out, dotp);
  __syncthreads();
  if (t < G2_BN) {
    atomicAdd(&colsum_mu[bn + t], s_mu[t]);
    atomicAdd(&colsum_y[bn + t], s_y[t]);
  }
}

// ---------------------------------------------------------------------------
// K4: out = dot/N - (1/N^2) * sum_d colsum_y[d]*colsum_mu[d]
// ---------------------------------------------------------------------------
__global__ __launch_bounds__(256) void finalize_kernel(
    const float* __restrict__ colsum_mu, const float* __restrict__ colsum_y,
    const float* __restrict__ dot_in, float* __restrict__ out) {
  __shared__ float partial[4];
  const int t = threadIdx.x;  // 256 threads, d = t
  float v = colsum_mu[t] * colsum_y[t];
#pragma unroll
  for (int off = 1; off < 64; off <<= 1) v += __shfl_xor(v, off);
  if ((t & 63) == 0) partial[t >> 6] = v;
  __syncthreads();
  if (t == 0) {
    float tot = partial[0] + partial[1] + partial[2] + partial[3];
    out[0] = dot_in[0] * (1.0f / 1024.0f) - tot * (1.0f / (1024.0f * 1024.0f));
  }
}

// ---------------------------------------------------------------------------
extern "C" void kernel_launch(void* const* d_in, const int* in_sizes, int n_in,
                              void* d_out, int out_size, void* d_ws, size_t ws_size,
                              hipStream_t stream) {
  const float* x  = (const float*)d_in[0];  // (1024, 512, 8, 8)
  const float* y  = (const float*)d_in[1];  // (1024, 256, 8, 8)
  const float* W1 = (const float*)d_in[2];  // (512, 512)
  const float* b1 = (const float*)d_in[3];  // (512,)
  const float* W2 = (const float*)d_in[4];  // (512, 256)
  const float* b2 = (const float*)d_in[5];  // (256,)
  float* out = (float*)d_out;

  char* ws = (char*)d_ws;
  float* x_vec = (float*)ws;                        // 1024*512 f32 = 2 MB
  float* y_vec = (float*)(ws + (2u << 20));         // 1024*256 f32 = 1 MB
  float* h     = (float*)(ws + (3u << 20));         // 1024*512 f32 = 2 MB
  float* accum = (float*)(ws + (5u << 20));         // colsum_mu[256], colsum_y[256], dot[1]
  float* colsum_mu = accum;
  float* colsum_y  = accum + 256;
  float* dotp      = accum + 512;

  hipMemsetAsync(accum, 0, 513 * sizeof(float), stream);

  // K1: 8192 waves for x + 4096 for y = 12288 waves = 3072 blocks of 256
  pool_kernel<<<3072, 256, 0, stream>>>(x, y, x_vec, y_vec);

  // K2: grid (512/32, 1024/64) = (16, 16)
  gemm1_kernel<<<dim3(16, 16), 256, 0, stream>>>(x_vec, W1, b1, h);

  // K3: grid (256/32, 1024/32) = (8, 32)
  gemm2_kernel<<<dim3(8, 32), 256, 0, stream>>>(h, W2, b2, y_vec,
                                                colsum_mu, colsum_y, dotp);

  // K4
  finalize_kernel<<<1, 256, 0, stream>>>(colsum_mu, colsum_y, dotp, out);
}

// Round 2
// 281.986 us; speedup vs baseline: 1.1486x; 1.1486x over previous
//
#include <hip/hip_runtime.h>

#define N_SAMP 1024
#define XC_DIM 512
#define YC_DIM 256
#define HID_DIM 512

// ---------------------------------------------------------------------------
// K1: fused spatial pooling. One thread per output element; 16 independent
// float4 loads kept live (high MLP), pure in-lane reduction, coalesced store.
// ---------------------------------------------------------------------------
__global__ __launch_bounds__(256) void pool_kernel(
    const float* __restrict__ x, const float* __restrict__ y,
    float* __restrict__ x_vec, float* __restrict__ y_vec) {
  const long e = (long)blockIdx.x * 256 + threadIdx.x;
  const long NX = (long)N_SAMP * XC_DIM;  // 524288
  const float4* p;
  float* dst;
  long o;
  if (e < NX) {
    p = (const float4*)x + e * 16;
    dst = x_vec; o = e;
  } else {
    p = (const float4*)y + (e - NX) * 16;
    dst = y_vec; o = e - NX;
  }
  float4 v[16];
#pragma unroll
  for (int j = 0; j < 16; ++j) v[j] = p[j];
  float s0 = 0.f, s1 = 0.f, s2 = 0.f, s3 = 0.f;
#pragma unroll
  for (int j = 0; j < 16; j += 4) {
    s0 += (v[j + 0].x + v[j + 0].y) + (v[j + 0].z + v[j + 0].w);
    s1 += (v[j + 1].x + v[j + 1].y) + (v[j + 1].z + v[j + 1].w);
    s2 += (v[j + 2].x + v[j + 2].y) + (v[j + 2].z + v[j + 2].w);
    s3 += (v[j + 3].x + v[j + 3].y) + (v[j + 3].z + v[j + 3].w);
  }
  dst[o] = ((s0 + s1) + (s2 + s3)) * (1.0f / 64.0f);
}

// ---------------------------------------------------------------------------
// K2: h_part[s] = x_vec @ W1[ksplit s]   (bias+relu deferred to K3's A-load)
// 64x64 tile, 256 thr, 4x4/thread, BK=16, splitK=4 -> grid (8,16,4)=512 blocks
// ---------------------------------------------------------------------------
#define TBK 16

__global__ __launch_bounds__(256) void gemm1_kernel(
    const float* __restrict__ A, const float* __restrict__ B,
    float* __restrict__ Hp) {
  const int K = 512, Nn = 512;
  __shared__ float As[TBK][68];  // [k][m], padded
  __shared__ float Bs[TBK][68];  // [k][n], padded
  const int t = threadIdx.x;
  const int bn = blockIdx.x * 64;
  const int bm = blockIdx.y * 64;
  const int ks = blockIdx.z;  // 0..3, each covers K-range of 128

  const int arow = t >> 2, acol = (t & 3) * 4;    // A: 64 rows x 16 k
  const int brow = t >> 4, bcol = (t & 15) * 4;   // B: 16 k x 64 n
  const int row0 = (t >> 4) * 4, col0 = (t & 15) * 4;

  float acc[4][4] = {};
  const int k0 = ks * 128;

  float4 av = *(const float4*)&A[(bm + arow) * K + k0 + acol];
  float4 bv = *(const float4*)&B[(k0 + brow) * Nn + bn + bcol];

  for (int it = 0; it < 8; ++it) {
    __syncthreads();
    As[acol + 0][arow] = av.x;
    As[acol + 1][arow] = av.y;
    As[acol + 2][arow] = av.z;
    As[acol + 3][arow] = av.w;
    *(float4*)&Bs[brow][bcol] = bv;
    __syncthreads();
    if (it < 7) {
      const int k1 = k0 + (it + 1) * TBK;
      av = *(const float4*)&A[(bm + arow) * K + k1 + acol];
      bv = *(const float4*)&B[(k1 + brow) * Nn + bn + bcol];
    }
#pragma unroll
    for (int kk = 0; kk < TBK; ++kk) {
      float4 a = *(const float4*)&As[kk][row0];
      float4 b = *(const float4*)&Bs[kk][col0];
      acc[0][0] += a.x * b.x; acc[0][1] += a.x * b.y; acc[0][2] += a.x * b.z; acc[0][3] += a.x * b.w;
      acc[1][0] += a.y * b.x; acc[1][1] += a.y * b.y; acc[1][2] += a.y * b.z; acc[1][3] += a.y * b.w;
      acc[2][0] += a.z * b.x; acc[2][1] += a.z * b.y; acc[2][2] += a.z * b.z; acc[2][3] += a.z * b.w;
      acc[3][0] += a.w * b.x; acc[3][1] += a.w * b.y; acc[3][2] += a.w * b.z; acc[3][3] += a.w * b.w;
    }
  }

  float* H = Hp + (long)ks * (N_SAMP * HID_DIM);
#pragma unroll
  for (int i = 0; i < 4; ++i) {
    float4 o;
    o.x = acc[i][0]; o.y = acc[i][1]; o.z = acc[i][2]; o.w = acc[i][3];
    *(float4*)&H[(long)(bm + row0 + i) * Nn + bn + col0] = o;
  }
}

// ---------------------------------------------------------------------------
// K3: mu_part[s] = relu(sum Hp + b1) @ W2[ksplit s]   (b2 deferred to K4)
// 64x64 tile, splitK=8 -> grid (4,16,8)=512 blocks
// ---------------------------------------------------------------------------
__global__ __launch_bounds__(256) void gemm2_kernel(
    const float* __restrict__ Hp, const float* __restrict__ b1,
    const float* __restrict__ B, float* __restrict__ Mup) {
  const int K = 512, Nn = 256;
  __shared__ float As[TBK][68];
  __shared__ float Bs[TBK][68];
  const int t = threadIdx.x;
  const int bn = blockIdx.x * 64;
  const int bm = blockIdx.y * 64;
  const int ks = blockIdx.z;  // 0..7, each covers K-range of 64

  const int arow = t >> 2, acol = (t & 3) * 4;
  const int brow = t >> 4, bcol = (t & 15) * 4;
  const int row0 = (t >> 4) * 4, col0 = (t & 15) * 4;
  const long HS = (long)N_SAMP * HID_DIM;

  float acc[4][4] = {};
  const int k0 = ks * 64;

  // A element = relu(h0+h1+h2+h3 + b1[k])
  long aidx = (long)(bm + arow) * K + k0 + acol;
  float4 a0 = *(const float4*)&Hp[aidx];
  float4 a1 = *(const float4*)&Hp[aidx + HS];
  float4 a2 = *(const float4*)&Hp[aidx + 2 * HS];
  float4 a3 = *(const float4*)&Hp[aidx + 3 * HS];
  float4 bb = *(const float4*)&b1[k0 + acol];
  float4 bv = *(const float4*)&B[(k0 + brow) * Nn + bn + bcol];

  for (int it = 0; it < 4; ++it) {
    float4 av;
    av.x = fmaxf(a0.x + a1.x + a2.x + a3.x + bb.x, 0.0f);
    av.y = fmaxf(a0.y + a1.y + a2.y + a3.y + bb.y, 0.0f);
    av.z = fmaxf(a0.z + a1.z + a2.z + a3.z + bb.z, 0.0f);
    av.w = fmaxf(a0.w + a1.w + a2.w + a3.w + bb.w, 0.0f);
    __syncthreads();
    As[acol + 0][arow] = av.x;
    As[acol + 1][arow] = av.y;
    As[acol + 2][arow] = av.z;
    As[acol + 3][arow] = av.w;
    *(float4*)&Bs[brow][bcol] = bv;
    __syncthreads();
    if (it < 3) {
      const int k1 = k0 + (it + 1) * TBK;
      aidx = (long)(bm + arow) * K + k1 + acol;
      a0 = *(const float4*)&Hp[aidx];
      a1 = *(const float4*)&Hp[aidx + HS];
      a2 = *(const float4*)&Hp[aidx + 2 * HS];
      a3 = *(const float4*)&Hp[aidx + 3 * HS];
      bb = *(const float4*)&b1[k1 + acol];
      bv = *(const float4*)&B[(k1 + brow) * Nn + bn + bcol];
    }
#pragma unroll
    for (int kk = 0; kk < TBK; ++kk) {
      float4 a = *(const float4*)&As[kk][row0];
      float4 b = *(const float4*)&Bs[kk][col0];
      acc[0][0] += a.x * b.x; acc[0][1] += a.x * b.y; acc[0][2] += a.x * b.z; acc[0][3] += a.x * b.w;
      acc[1][0] += a.y * b.x; acc[1][1] += a.y * b.y; acc[1][2] += a.y * b.z; acc[1][3] += a.y * b.w;
      acc[2][0] += a.z * b.x; acc[2][1] += a.z * b.y; acc[2][2] += a.z * b.z; acc[2][3] += a.z * b.w;
      acc[3][0] += a.w * b.x; acc[3][1] += a.w * b.y; acc[3][2] += a.w * b.z; acc[3][3] += a.w * b.w;
    }
  }

  float* M = Mup + (long)ks * (N_SAMP * YC_DIM);
#pragma unroll
  for (int i = 0; i < 4; ++i) {
    float4 o;
    o.x = acc[i][0]; o.y = acc[i][1]; o.z = acc[i][2]; o.w = acc[i][3];
    *(float4*)&M[(long)(bm + row0 + i) * Nn + bn + col0] = o;
  }
}

// ---------------------------------------------------------------------------
// K4: fold mu = sum Mup + b2; accumulate dot(mu,y), colsum_mu, colsum_y
// 256 blocks x 256 threads; thread t owns column d=t, 4 rows per block.
// ---------------------------------------------------------------------------
__global__ __launch_bounds__(256) void reduce_kernel(
    const float* __restrict__ Mup, const float* __restrict__ b2,
    const float* __restrict__ yv, float* __restrict__ colsum_mu,
    float* __restrict__ colsum_y, float* __restrict__ dot_out) {
  const int d = threadIdx.x;
  const int n0 = blockIdx.x * 4;
  const long MS = (long)N_SAMP * YC_DIM;
  const float bb = b2[d];
  float cm = 0.f, cy = 0.f, dp = 0.f;
#pragma unroll
  for (int r = 0; r < 4; ++r) {
    const long idx = (long)(n0 + r) * YC_DIM + d;
    float mu = bb;
#pragma unroll
    for (int s = 0; s < 8; ++s) mu += Mup[idx + s * MS];
    const float yy = yv[idx];
    dp += mu * yy;
    cm += mu;
    cy += yy;
  }
  atomicAdd(&colsum_mu[d], cm);
  atomicAdd(&colsum_y[d], cy);
#pragma unroll
  for (int off = 1; off < 64; off <<= 1) dp += __shfl_xor(dp, off);
  if ((d & 63) == 0) atomicAdd(dot_out, dp);
}

// ---------------------------------------------------------------------------
// K5: out = dot/N - (1/N^2) * sum_d colsum_y[d]*colsum_mu[d]
// ---------------------------------------------------------------------------
__global__ __launch_bounds__(256) void finalize_kernel(
    const float* __restrict__ colsum_mu, const float* __restrict__ colsum_y,
    const float* __restrict__ dot_in, float* __restrict__ out) {
  __shared__ float partial[4];
  const int t = threadIdx.x;
  float v = colsum_mu[t] * colsum_y[t];
#pragma unroll
  for (int off = 1; off < 64; off <<= 1) v += __shfl_xor(v, off);
  if ((t & 63) == 0) partial[t >> 6] = v;
  __syncthreads();
  if (t == 0) {
    float tot = partial[0] + partial[1] + partial[2] + partial[3];
    out[0] = dot_in[0] * (1.0f / 1024.0f) - tot * (1.0f / (1024.0f * 1024.0f));
  }
}

// ---------------------------------------------------------------------------
extern "C" void kernel_launch(void* const* d_in, const int* in_sizes, int n_in,
                              void* d_out, int out_size, void* d_ws, size_t ws_size,
                              hipStream_t stream) {
  const float* x  = (const float*)d_in[0];
  const float* y  = (const float*)d_in[1];
  const float* W1 = (const float*)d_in[2];
  const float* b1 = (const float*)d_in[3];
  const float* W2 = (const float*)d_in[4];
  const float* b2 = (const float*)d_in[5];
  float* out = (float*)d_out;

  char* ws = (char*)d_ws;
  float* x_vec = (float*)ws;                    // 2 MB
  float* y_vec = (float*)(ws + (2lu << 20));    // 1 MB
  float* Hp    = (float*)(ws + (4lu << 20));    // 4 x 2 MB
  float* Mup   = (float*)(ws + (12lu << 20));   // 8 x 1 MB
  float* accum = (float*)(ws + (20lu << 20));   // colsums + dot
  float* colsum_mu = accum;
  float* colsum_y  = accum + 256;
  float* dotp      = accum + 512;

  hipMemsetAsync(accum, 0, 513 * sizeof(float), stream);

  pool_kernel<<<3072, 256, 0, stream>>>(x, y, x_vec, y_vec);

  gemm1_kernel<<<dim3(8, 16, 4), 256, 0, stream>>>(x_vec, W1, Hp);

  gemm2_kernel<<<dim3(4, 16, 8), 256, 0, stream>>>(Hp, b1, W2, Mup);

  reduce_kernel<<<256, 256, 0, stream>>>(Mup, b2, y_vec, colsum_mu,
                                         colsum_y, dotp);

  finalize_kernel<<<1, 256, 0, stream>>>(colsum_mu, colsum_y, dotp, out);
}

// Round 3
// 276.278 us; speedup vs baseline: 1.1723x; 1.0207x over previous
//
#include <hip/hip_runtime.h>

#define N_SAMP 1024
#define XC_DIM 512
#define YC_DIM 256
#define HID_DIM 512

// ---------------------------------------------------------------------------
// K1: fused spatial pooling, coalesced + LDS transpose.
// Block handles 256 consecutive outputs = 4096 float4 = 64 KB contiguous.
// Phase 1: 16 lane-contiguous float4 loads/thread (1024 B per wave instr),
//          4->1 in-register, store partial to LDS row o, slot j (stride 17).
// Phase 2: thread t row-sums its 16 partials (stride-17 rows: 2-way, free).
// ---------------------------------------------------------------------------
__global__ __launch_bounds__(256) void pool_kernel(
    const float* __restrict__ x, const float* __restrict__ y,
    float* __restrict__ x_vec, float* __restrict__ y_vec) {
  __shared__ float s[256 * 17];
  const int t = threadIdx.x;
  const long blk = blockIdx.x;
  const float4* src;
  float* dst;
  long obase;
  if (blk < 2048) {            // x: 524288 outputs = 2048 blocks
    src = (const float4*)x; dst = x_vec; obase = blk * 256;
  } else {                     // y: 262144 outputs = 1024 blocks
    src = (const float4*)y; dst = y_vec; obase = (blk - 2048) * 256;
  }
  const float4* p = src + obase * 16;

  float4 v[16];
#pragma unroll
  for (int k = 0; k < 16; ++k) v[k] = p[k * 256 + t];
#pragma unroll
  for (int k = 0; k < 16; ++k) {
    float sv = (v[k].x + v[k].y) + (v[k].z + v[k].w);
    const int o = k * 16 + (t >> 4);  // output row this partial belongs to
    const int j = t & 15;             // slot within the row
    s[o * 17 + j] = sv;
  }
  __syncthreads();
  float acc = 0.f;
#pragma unroll
  for (int j = 0; j < 16; ++j) acc += s[t * 17 + j];
  dst[obase + t] = acc * (1.0f / 64.0f);
}

// ---------------------------------------------------------------------------
// K2: Hp[s] = x_vec @ W1[k-chunk s]. 64x64 tile, 4x4/thread, BK=16,
// splitK=8 (chunk 64 = 4 iters) -> grid (8,16,8) = 1024 blocks = 4/CU.
// ---------------------------------------------------------------------------
#define TBK 16

__global__ __launch_bounds__(256) void gemm1_kernel(
    const float* __restrict__ A, const float* __restrict__ B,
    float* __restrict__ Hp) {
  const int K = 512, Nn = 512;
  __shared__ float As[TBK][68];
  __shared__ float Bs[TBK][68];
  const int t = threadIdx.x;
  const int bn = blockIdx.x * 64;
  const int bm = blockIdx.y * 64;
  const int ks = blockIdx.z;          // 0..7, K-chunk of 64

  const int arow = t >> 2, acol = (t & 3) * 4;
  const int brow = t >> 4, bcol = (t & 15) * 4;
  const int row0 = (t >> 4) * 4, col0 = (t & 15) * 4;

  float acc[4][4] = {};
  const int k0 = ks * 64;

  float4 av = *(const float4*)&A[(bm + arow) * K + k0 + acol];
  float4 bv = *(const float4*)&B[(k0 + brow) * Nn + bn + bcol];

  for (int it = 0; it < 4; ++it) {
    __syncthreads();
    As[acol + 0][arow] = av.x;
    As[acol + 1][arow] = av.y;
    As[acol + 2][arow] = av.z;
    As[acol + 3][arow] = av.w;
    *(float4*)&Bs[brow][bcol] = bv;
    __syncthreads();
    if (it < 3) {
      const int k1 = k0 + (it + 1) * TBK;
      av = *(const float4*)&A[(bm + arow) * K + k1 + acol];
      bv = *(const float4*)&B[(k1 + brow) * Nn + bn + bcol];
    }
#pragma unroll
    for (int kk = 0; kk < TBK; ++kk) {
      float4 a = *(const float4*)&As[kk][row0];
      float4 b = *(const float4*)&Bs[kk][col0];
      acc[0][0] += a.x * b.x; acc[0][1] += a.x * b.y; acc[0][2] += a.x * b.z; acc[0][3] += a.x * b.w;
      acc[1][0] += a.y * b.x; acc[1][1] += a.y * b.y; acc[1][2] += a.y * b.z; acc[1][3] += a.y * b.w;
      acc[2][0] += a.z * b.x; acc[2][1] += a.z * b.y; acc[2][2] += a.z * b.z; acc[2][3] += a.z * b.w;
      acc[3][0] += a.w * b.x; acc[3][1] += a.w * b.y; acc[3][2] += a.w * b.z; acc[3][3] += a.w * b.w;
    }
  }

  float* H = Hp + (long)ks * (N_SAMP * HID_DIM);
#pragma unroll
  for (int i = 0; i < 4; ++i) {
    float4 o;
    o.x = acc[i][0]; o.y = acc[i][1]; o.z = acc[i][2]; o.w = acc[i][3];
    *(float4*)&H[(long)(bm + row0 + i) * Nn + bn + col0] = o;
  }
}

// ---------------------------------------------------------------------------
// K2b: h = relu(sum_s Hp[s] + b1). 131072 float4, 512 blocks.
// ---------------------------------------------------------------------------
__global__ __launch_bounds__(256) void foldh_kernel(
    const float* __restrict__ Hp, const float* __restrict__ b1,
    float* __restrict__ h) {
  const long i = (long)blockIdx.x * 256 + threadIdx.x;  // float4 index
  const long HS4 = (long)N_SAMP * HID_DIM / 4;
  const float4* Hp4 = (const float4*)Hp;
  float4 a = Hp4[i];
#pragma unroll
  for (int s = 1; s < 8; ++s) {
    float4 b = Hp4[i + s * HS4];
    a.x += b.x; a.y += b.y; a.z += b.z; a.w += b.w;
  }
  const float4 bb = ((const float4*)b1)[i & 127];  // 512 cols / 4
  float4 o;
  o.x = fmaxf(a.x + bb.x, 0.f);
  o.y = fmaxf(a.y + bb.y, 0.f);
  o.z = fmaxf(a.z + bb.z, 0.f);
  o.w = fmaxf(a.w + bb.w, 0.f);
  ((float4*)h)[i] = o;
}

// ---------------------------------------------------------------------------
// K3: Mup[s] = h @ W2[k-chunk s]. splitK=8 -> grid (4,16,8) = 512 blocks.
// ---------------------------------------------------------------------------
__global__ __launch_bounds__(256) void gemm2_kernel(
    const float* __restrict__ A, const float* __restrict__ B,
    float* __restrict__ Mup) {
  const int K = 512, Nn = 256;
  __shared__ float As[TBK][68];
  __shared__ float Bs[TBK][68];
  const int t = threadIdx.x;
  const int bn = blockIdx.x * 64;
  const int bm = blockIdx.y * 64;
  const int ks = blockIdx.z;          // 0..7

  const int arow = t >> 2, acol = (t & 3) * 4;
  const int brow = t >> 4, bcol = (t & 15) * 4;
  const int row0 = (t >> 4) * 4, col0 = (t & 15) * 4;

  float acc[4][4] = {};
  const int k0 = ks * 64;

  float4 av = *(const float4*)&A[(bm + arow) * K + k0 + acol];
  float4 bv = *(const float4*)&B[(k0 + brow) * Nn + bn + bcol];

  for (int it = 0; it < 4; ++it) {
    __syncthreads();
    As[acol + 0][arow] = av.x;
    As[acol + 1][arow] = av.y;
    As[acol + 2][arow] = av.z;
    As[acol + 3][arow] = av.w;
    *(float4*)&Bs[brow][bcol] = bv;
    __syncthreads();
    if (it < 3) {
      const int k1 = k0 + (it + 1) * TBK;
      av = *(const float4*)&A[(bm + arow) * K + k1 + acol];
      bv = *(const float4*)&B[(k1 + brow) * Nn + bn + bcol];
    }
#pragma unroll
    for (int kk = 0; kk < TBK; ++kk) {
      float4 a = *(const float4*)&As[kk][row0];
      float4 b = *(const float4*)&Bs[kk][col0];
      acc[0][0] += a.x * b.x; acc[0][1] += a.x * b.y; acc[0][2] += a.x * b.z; acc[0][3] += a.x * b.w;
      acc[1][0] += a.y * b.x; acc[1][1] += a.y * b.y; acc[1][2] += a.y * b.z; acc[1][3] += a.y * b.w;
      acc[2][0] += a.z * b.x; acc[2][1] += a.z * b.y; acc[2][2] += a.z * b.z; acc[2][3] += a.z * b.w;
      acc[3][0] += a.w * b.x; acc[3][1] += a.w * b.y; acc[3][2] += a.w * b.z; acc[3][3] += a.w * b.w;
    }
  }

  float* M = Mup + (long)ks * (N_SAMP * YC_DIM);
#pragma unroll
  for (int i = 0; i < 4; ++i) {
    float4 o;
    o.x = acc[i][0]; o.y = acc[i][1]; o.z = acc[i][2]; o.w = acc[i][3];
    *(float4*)&M[(long)(bm + row0 + i) * Nn + bn + col0] = o;
  }
}

// ---------------------------------------------------------------------------
// K4: fold mu = sum Mup + b2; accumulate dot(mu,y), colsum_mu, colsum_y.
// 64 blocks x 256 threads; thread t owns column d=t, 16 rows per block.
// ---------------------------------------------------------------------------
__global__ __launch_bounds__(256) void reduce_kernel(
    const float* __restrict__ Mup, const float* __restrict__ b2,
    const float* __restrict__ yv, float* __restrict__ colsum_mu,
    float* __restrict__ colsum_y, float* __restrict__ dot_out) {
  const int d = threadIdx.x;
  const int n0 = blockIdx.x * 16;
  const long MS = (long)N_SAMP * YC_DIM;
  const float bb = b2[d];
  float cm = 0.f, cy = 0.f, dp = 0.f;
#pragma unroll 4
  for (int r = 0; r < 16; ++r) {
    const long idx = (long)(n0 + r) * YC_DIM + d;
    float mu = bb;
#pragma unroll
    for (int s = 0; s < 8; ++s) mu += Mup[idx + s * MS];
    const float yy = yv[idx];
    dp += mu * yy;
    cm += mu;
    cy += yy;
  }
  atomicAdd(&colsum_mu[d], cm);
  atomicAdd(&colsum_y[d], cy);
#pragma unroll
  for (int off = 1; off < 64; off <<= 1) dp += __shfl_xor(dp, off);
  if ((d & 63) == 0) atomicAdd(dot_out, dp);
}

// ---------------------------------------------------------------------------
// K5: out = dot/N - (1/N^2) * sum_d colsum_y[d]*colsum_mu[d]
// ---------------------------------------------------------------------------
__global__ __launch_bounds__(256) void finalize_kernel(
    const float* __restrict__ colsum_mu, const float* __restrict__ colsum_y,
    const float* __restrict__ dot_in, float* __restrict__ out) {
  __shared__ float partial[4];
  const int t = threadIdx.x;
  float v = colsum_mu[t] * colsum_y[t];
#pragma unroll
  for (int off = 1; off < 64; off <<= 1) v += __shfl_xor(v, off);
  if ((t & 63) == 0) partial[t >> 6] = v;
  __syncthreads();
  if (t == 0) {
    float tot = partial[0] + partial[1] + partial[2] + partial[3];
    out[0] = dot_in[0] * (1.0f / 1024.0f) - tot * (1.0f / (1024.0f * 1024.0f));
  }
}

// ---------------------------------------------------------------------------
extern "C" void kernel_launch(void* const* d_in, const int* in_sizes, int n_in,
                              void* d_out, int out_size, void* d_ws, size_t ws_size,
                              hipStream_t stream) {
  const float* x  = (const float*)d_in[0];
  const float* y  = (const float*)d_in[1];
  const float* W1 = (const float*)d_in[2];
  const float* b1 = (const float*)d_in[3];
  const float* W2 = (const float*)d_in[4];
  const float* b2 = (const float*)d_in[5];
  float* out = (float*)d_out;

  char* ws = (char*)d_ws;
  float* x_vec = (float*)ws;                    // 2 MB
  float* y_vec = (float*)(ws + (2lu << 20));    // 1 MB
  float* h     = (float*)(ws + (3lu << 20));    // 2 MB
  float* Hp    = (float*)(ws + (8lu << 20));    // 8 x 2 MB = 16 MB
  float* Mup   = (float*)(ws + (24lu << 20));   // 8 x 1 MB = 8 MB
  float* accum = (float*)(ws + (32lu << 20));
  float* colsum_mu = accum;
  float* colsum_y  = accum + 256;
  float* dotp      = accum + 512;

  hipMemsetAsync(accum, 0, 513 * sizeof(float), stream);

  pool_kernel<<<3072, 256, 0, stream>>>(x, y, x_vec, y_vec);

  gemm1_kernel<<<dim3(8, 16, 8), 256, 0, stream>>>(x_vec, W1, Hp);

  foldh_kernel<<<512, 256, 0, stream>>>(Hp, b1, h);

  gemm2_kernel<<<dim3(4, 16, 8), 256, 0, stream>>>(h, W2, Mup);

  reduce_kernel<<<64, 256, 0, stream>>>(Mup, b2, y_vec, colsum_mu,
                                        colsum_y, dotp);

  finalize_kernel<<<1, 256, 0, stream>>>(colsum_mu, colsum_y, dotp, out);
}

// Round 4
// 275.611 us; speedup vs baseline: 1.1752x; 1.0024x over previous
//
#include <hip/hip_runtime.h>

#define N_SAMP 1024
#define XC_DIM 512
#define YC_DIM 256
#define HID_DIM 512

// ---------------------------------------------------------------------------
// K1: fused spatial pooling, coalesced + LDS transpose.
// __launch_bounds__(256,2) -> up to 128 VGPRs so all 16 float4 loads stay in
// flight per wave (r1-r3 all got squeezed to <=36 VGPRs = ~4 outstanding
// loads, which is why coalescing didn't matter under drain-inflated latency).
// ---------------------------------------------------------------------------
__global__ __launch_bounds__(256, 2) void pool_kernel(
    const float* __restrict__ x, const float* __restrict__ y,
    float* __restrict__ x_vec, float* __restrict__ y_vec) {
  __shared__ float s[256 * 17];
  const int t = threadIdx.x;
  const long blk = blockIdx.x;
  const float4* src;
  float* dst;
  long obase;
  if (blk < 2048) {            // x: 524288 outputs = 2048 blocks
    src = (const float4*)x; dst = x_vec; obase = blk * 256;
  } else {                     // y: 262144 outputs = 1024 blocks
    src = (const float4*)y; dst = y_vec; obase = (blk - 2048) * 256;
  }
  const float4* p = src + obase * 16;

  // Issue all 16 coalesced loads back-to-back; registers stay live.
  float4 v[16];
#pragma unroll
  for (int k = 0; k < 16; ++k) v[k] = p[k * 256 + t];

#pragma unroll
  for (int k = 0; k < 16; ++k) {
    float sv = (v[k].x + v[k].y) + (v[k].z + v[k].w);
    const int o = k * 16 + (t >> 4);
    const int j = t & 15;
    s[o * 17 + j] = sv;
  }
  __syncthreads();
  float acc = 0.f;
#pragma unroll
  for (int j = 0; j < 16; ++j) acc += s[t * 17 + j];
  dst[obase + t] = acc * (1.0f / 64.0f);
}

// ---------------------------------------------------------------------------
// K2: Hp[s] = x_vec @ W1[k-chunk s]. 64x64 tile, 4x4/thread, BK=16,
// splitK=4 (chunk 128 = 8 iters) -> grid (8,16,4) = 512 blocks = 2/CU.
// ---------------------------------------------------------------------------
#define TBK 16

__global__ __launch_bounds__(256) void gemm1_kernel(
    const float* __restrict__ A, const float* __restrict__ B,
    float* __restrict__ Hp) {
  const int K = 512, Nn = 512;
  __shared__ float As[TBK][68];
  __shared__ float Bs[TBK][68];
  const int t = threadIdx.x;
  const int bn = blockIdx.x * 64;
  const int bm = blockIdx.y * 64;
  const int ks = blockIdx.z;          // 0..3, K-chunk of 128

  const int arow = t >> 2, acol = (t & 3) * 4;
  const int brow = t >> 4, bcol = (t & 15) * 4;
  const int row0 = (t >> 4) * 4, col0 = (t & 15) * 4;

  float acc[4][4] = {};
  const int k0 = ks * 128;

  float4 av = *(const float4*)&A[(bm + arow) * K + k0 + acol];
  float4 bv = *(const float4*)&B[(k0 + brow) * Nn + bn + bcol];

  for (int it = 0; it < 8; ++it) {
    __syncthreads();
    As[acol + 0][arow] = av.x;
    As[acol + 1][arow] = av.y;
    As[acol + 2][arow] = av.z;
    As[acol + 3][arow] = av.w;
    *(float4*)&Bs[brow][bcol] = bv;
    __syncthreads();
    if (it < 7) {
      const int k1 = k0 + (it + 1) * TBK;
      av = *(const float4*)&A[(bm + arow) * K + k1 + acol];
      bv = *(const float4*)&B[(k1 + brow) * Nn + bn + bcol];
    }
#pragma unroll
    for (int kk = 0; kk < TBK; ++kk) {
      float4 a = *(const float4*)&As[kk][row0];
      float4 b = *(const float4*)&Bs[kk][col0];
      acc[0][0] += a.x * b.x; acc[0][1] += a.x * b.y; acc[0][2] += a.x * b.z; acc[0][3] += a.x * b.w;
      acc[1][0] += a.y * b.x; acc[1][1] += a.y * b.y; acc[1][2] += a.y * b.z; acc[1][3] += a.y * b.w;
      acc[2][0] += a.z * b.x; acc[2][1] += a.z * b.y; acc[2][2] += a.z * b.z; acc[2][3] += a.z * b.w;
      acc[3][0] += a.w * b.x; acc[3][1] += a.w * b.y; acc[3][2] += a.w * b.z; acc[3][3] += a.w * b.w;
    }
  }

  float* H = Hp + (long)ks * (N_SAMP * HID_DIM);
#pragma unroll
  for (int i = 0; i < 4; ++i) {
    float4 o;
    o.x = acc[i][0]; o.y = acc[i][1]; o.z = acc[i][2]; o.w = acc[i][3];
    *(float4*)&H[(long)(bm + row0 + i) * Nn + bn + col0] = o;
  }
}

// ---------------------------------------------------------------------------
// K3: Mup[s] = relu(sum_{p=0..3} Hp[p] + b1) @ W2[k-chunk s].
// A built inline from the 4 gemm1 partials (h never materialized).
// splitK=8 -> grid (4,16,8) = 512 blocks.
// ---------------------------------------------------------------------------
__global__ __launch_bounds__(256) void gemm2_kernel(
    const float* __restrict__ Hp, const float* __restrict__ b1,
    const float* __restrict__ B, float* __restrict__ Mup) {
  const int K = 512, Nn = 256;
  __shared__ float As[TBK][68];
  __shared__ float Bs[TBK][68];
  const int t = threadIdx.x;
  const int bn = blockIdx.x * 64;
  const int bm = blockIdx.y * 64;
  const int ks = blockIdx.z;          // 0..7, K-chunk of 64
  const long HS = (long)N_SAMP * HID_DIM;

  const int arow = t >> 2, acol = (t & 3) * 4;
  const int brow = t >> 4, bcol = (t & 15) * 4;
  const int row0 = (t >> 4) * 4, col0 = (t & 15) * 4;

  float acc[4][4] = {};
  const int k0 = ks * 64;

  long aidx = (long)(bm + arow) * K + k0 + acol;
  float4 a0 = *(const float4*)&Hp[aidx];
  float4 a1 = *(const float4*)&Hp[aidx + HS];
  float4 a2 = *(const float4*)&Hp[aidx + 2 * HS];
  float4 a3 = *(const float4*)&Hp[aidx + 3 * HS];
  float4 bb = *(const float4*)&b1[k0 + acol];
  float4 bv = *(const float4*)&B[(k0 + brow) * Nn + bn + bcol];

  for (int it = 0; it < 4; ++it) {
    float4 av;
    av.x = fmaxf(a0.x + a1.x + a2.x + a3.x + bb.x, 0.0f);
    av.y = fmaxf(a0.y + a1.y + a2.y + a3.y + bb.y, 0.0f);
    av.z = fmaxf(a0.z + a1.z + a2.z + a3.z + bb.z, 0.0f);
    av.w = fmaxf(a0.w + a1.w + a2.w + a3.w + bb.w, 0.0f);
    __syncthreads();
    As[acol + 0][arow] = av.x;
    As[acol + 1][arow] = av.y;
    As[acol + 2][arow] = av.z;
    As[acol + 3][arow] = av.w;
    *(float4*)&Bs[brow][bcol] = bv;
    __syncthreads();
    if (it < 3) {
      const int k1 = k0 + (it + 1) * TBK;
      aidx = (long)(bm + arow) * K + k1 + acol;
      a0 = *(const float4*)&Hp[aidx];
      a1 = *(const float4*)&Hp[aidx + HS];
      a2 = *(const float4*)&Hp[aidx + 2 * HS];
      a3 = *(const float4*)&Hp[aidx + 3 * HS];
      bb = *(const float4*)&b1[k1 + acol];
      bv = *(const float4*)&B[(k1 + brow) * Nn + bn + bcol];
    }
#pragma unroll
    for (int kk = 0; kk < TBK; ++kk) {
      float4 a = *(const float4*)&As[kk][row0];
      float4 b = *(const float4*)&Bs[kk][col0];
      acc[0][0] += a.x * b.x; acc[0][1] += a.x * b.y; acc[0][2] += a.x * b.z; acc[0][3] += a.x * b.w;
      acc[1][0] += a.y * b.x; acc[1][1] += a.y * b.y; acc[1][2] += a.y * b.z; acc[1][3] += a.y * b.w;
      acc[2][0] += a.z * b.x; acc[2][1] += a.z * b.y; acc[2][2] += a.z * b.z; acc[2][3] += a.z * b.w;
      acc[3][0] += a.w * b.x; acc[3][1] += a.w * b.y; acc[3][2] += a.w * b.z; acc[3][3] += a.w * b.w;
    }
  }

  float* M = Mup + (long)ks * (N_SAMP * YC_DIM);
#pragma unroll
  for (int i = 0; i < 4; ++i) {
    float4 o;
    o.x = acc[i][0]; o.y = acc[i][1]; o.z = acc[i][2]; o.w = acc[i][3];
    *(float4*)&M[(long)(bm + row0 + i) * Nn + bn + col0] = o;
  }
}

// ---------------------------------------------------------------------------
// K4: fold mu = sum Mup + b2; accumulate dot(mu,y), colsum_mu, colsum_y.
// ---------------------------------------------------------------------------
__global__ __launch_bounds__(256) void reduce_kernel(
    const float* __restrict__ Mup, const float* __restrict__ b2,
    const float* __restrict__ yv, float* __restrict__ colsum_mu,
    float* __restrict__ colsum_y, float* __restrict__ dot_out) {
  const int d = threadIdx.x;
  const int n0 = blockIdx.x * 16;
  const long MS = (long)N_SAMP * YC_DIM;
  const float bb = b2[d];
  float cm = 0.f, cy = 0.f, dp = 0.f;
#pragma unroll 4
  for (int r = 0; r < 16; ++r) {
    const long idx = (long)(n0 + r) * YC_DIM + d;
    float mu = bb;
#pragma unroll
    for (int s = 0; s < 8; ++s) mu += Mup[idx + s * MS];
    const float yy = yv[idx];
    dp += mu * yy;
    cm += mu;
    cy += yy;
  }
  atomicAdd(&colsum_mu[d], cm);
  atomicAdd(&colsum_y[d], cy);
#pragma unroll
  for (int off = 1; off < 64; off <<= 1) dp += __shfl_xor(dp, off);
  if ((d & 63) == 0) atomicAdd(dot_out, dp);
}

// ---------------------------------------------------------------------------
// K5: out = dot/N - (1/N^2) * sum_d colsum_y[d]*colsum_mu[d]
// ---------------------------------------------------------------------------
__global__ __launch_bounds__(256) void finalize_kernel(
    const float* __restrict__ colsum_mu, const float* __restrict__ colsum_y,
    const float* __restrict__ dot_in, float* __restrict__ out) {
  __shared__ float partial[4];
  const int t = threadIdx.x;
  float v = colsum_mu[t] * colsum_y[t];
#pragma unroll
  for (int off = 1; off < 64; off <<= 1) v += __shfl_xor(v, off);
  if ((t & 63) == 0) partial[t >> 6] = v;
  __syncthreads();
  if (t == 0) {
    float tot = partial[0] + partial[1] + partial[2] + partial[3];
    out[0] = dot_in[0] * (1.0f / 1024.0f) - tot * (1.0f / (1024.0f * 1024.0f));
  }
}

// ---------------------------------------------------------------------------
extern "C" void kernel_launch(void* const* d_in, const int* in_sizes, int n_in,
                              void* d_out, int out_size, void* d_ws, size_t ws_size,
                              hipStream_t stream) {
  const float* x  = (const float*)d_in[0];
  const float* y  = (const float*)d_in[1];
  const float* W1 = (const float*)d_in[2];
  const float* b1 = (const float*)d_in[3];
  const float* W2 = (const float*)d_in[4];
  const float* b2 = (const float*)d_in[5];
  float* out = (float*)d_out;

  char* ws = (char*)d_ws;
  float* x_vec = (float*)ws;                    // 2 MB
  float* y_vec = (float*)(ws + (2lu << 20));    // 1 MB
  float* Hp    = (float*)(ws + (4lu << 20));    // 4 x 2 MB = 8 MB
  float* Mup   = (float*)(ws + (12lu << 20));   // 8 x 1 MB = 8 MB
  float* accum = (float*)(ws + (20lu << 20));
  float* colsum_mu = accum;
  float* colsum_y  = accum + 256;
  float* dotp      = accum + 512;

  hipMemsetAsync(accum, 0, 513 * sizeof(float), stream);

  pool_kernel<<<3072, 256, 0, stream>>>(x, y, x_vec, y_vec);

  gemm1_kernel<<<dim3(8, 16, 4), 256, 0, stream>>>(x_vec, W1, Hp);

  gemm2_kernel<<<dim3(4, 16, 8), 256, 0, stream>>>(Hp, b1, W2, Mup);

  reduce_kernel<<<64, 256, 0, stream>>>(Mup, b2, y_vec, colsum_mu,
                                        colsum_y, dotp);

  finalize_kernel<<<1, 256, 0, stream>>>(colsum_mu, colsum_y, dotp, out);
}